// Round 19
// baseline (207.276 us; speedup 1.0000x reference)
//
#include <hip/hip_runtime.h>
#include <hip/hip_bf16.h>

// CrossNetMoE fully fused, BT=64 rows/WG, 512 threads, grid=256 (1 WG/CU).
// L=3, E=4, D=1024, R=64, B=16384. LDS 160KB: s_xl 128KB + s_v 32KB.
// R19 = R18 with the G1-head prefetch HALVED (kt 0..1, 24 regs, was 48).
// R18 data: prefetch mechanism worked (FETCH 142->100MB) but 48-reg head +
// ~70-reg epilogue tail crossed the 128-VGPR hard cap -> spill (WRITE
// 67->106MB) ate the win. Dose correction, not direction change.
// Heads kept: G1 kt0-1 pre-top-barrier; C-frags pre-barrier-2a; U kt=0
// pre-barrier-2 (16 regs each, low-pressure windows).
// MFMA 16x16x32_f16 operand-swapped: D row(4lhi+r)=weight axis, col(l16)=m.

typedef _Float16 f16;
typedef f16  f16x4v __attribute__((ext_vector_type(4)));
typedef f16  f16x8 __attribute__((ext_vector_type(8)));
typedef float f32x4 __attribute__((ext_vector_type(4)));

#define B_TOT 16384
#define DDIM  1024
#define RLOW  64
#define NEXP  4
#define NLAY  3
#define BT    64

__device__ __forceinline__ float ftanh(float x) {
    float e2 = __expf(2.0f * x);          // inf-safe: ->1 / ->-1
    return 1.0f - 2.0f / (e2 + 1.0f);
}
__device__ __forceinline__ f32x4 mfma16(f16x8 a, f16x8 b, f32x4 c) {
    return __builtin_amdgcn_mfma_f32_16x16x32_f16(a, b, c, 0, 0, 0);
}
// swizzled byte offsets: row-stride 2048B (s_xl) / 512B (s_v); XOR bits 4-6
__device__ __forceinline__ int xl_off(int row, int col) {
    return row * 2048 + ((col * 2) ^ ((row & 7) << 4));
}
__device__ __forceinline__ int sv_off(int row, int col) {
    return row * 512 + ((col * 2) ^ ((row & 7) << 4));
}

__global__ void cast_f32_to_f16(const float* __restrict__ in,
                                f16* __restrict__ out, int n4) {
    int i = blockIdx.x * 256 + threadIdx.x;
    if (i < n4) {
        float4 v = reinterpret_cast<const float4*>(in)[i];
        f16 h0 = (f16)v.x, h1 = (f16)v.y, h2 = (f16)v.z, h3 = (f16)v.w;
        short4 pk;
        pk.x = __builtin_bit_cast(short, h0); pk.y = __builtin_bit_cast(short, h1);
        pk.z = __builtin_bit_cast(short, h2); pk.w = __builtin_bit_cast(short, h3);
        reinterpret_cast<short4*>(out)[i] = pk;
    }
}

// Wgh[l][16][1024] f16: rows 0-3 = Wg experts, rows 4-15 = 0.
__global__ void build_wgh(const float* __restrict__ Wg, f16* __restrict__ Wgh) {
    int i = blockIdx.x * 256 + threadIdx.x;          // < 3*16*1024
    int l = i >> 14, r = (i >> 10) & 15, k = i & 1023;
    f16 v = (f16)0.f;
    if (r < NEXP) v = (f16)Wg[(size_t)(l * NEXP + r) * DDIM + k];
    Wgh[i] = v;
}

__global__ __launch_bounds__(512, 1) void crossnet_fused(
    const float* __restrict__ x, float* __restrict__ out,
    const f16* __restrict__ Uh,   // [L][E][D][R]
    const f16* __restrict__ Vh,   // [L][256][1024]
    const f16* __restrict__ Ch,   // [L][E][64][64]
    const f16* __restrict__ Wgh,  // [L][16][1024]
    const float* __restrict__ bias)  // [L][1024]
{
    __shared__ f16 s_xl[BT * 1024];   // 128 KB, swizzled
    __shared__ f16 s_v[BT * 256];     //  32 KB, swizzled (v then p)

    const int tid  = threadIdx.x;
    const int lane = tid & 63;
    const int wv   = tid >> 6;        // 0..7
    const int l16  = lane & 15;
    const int lhi  = lane >> 4;       // 0..3
    const int row0 = blockIdx.x * BT;
    const int eown = wv >> 1;         // this wave's expert for GEMM-2
    const int hown = wv & 1;

    char* const xlb = (char*)s_xl;
    char* const svb = (char*)s_v;

    // ---- stage x -> s_xl (f16, swizzled): 64 rows x 1024 cols
#pragma unroll
    for (int j = 0; j < 16; ++j) {
        int f = tid + j * 512;        // 0..8191
        int row = f >> 7, seg = f & 127;
        const float4* sp = reinterpret_cast<const float4*>(
            x + (size_t)(row0 + row) * DDIM + seg * 8);
        float4 a = sp[0], b = sp[1];
        f16x8 h;
        h[0]=(f16)a.x; h[1]=(f16)a.y; h[2]=(f16)a.z; h[3]=(f16)a.w;
        h[4]=(f16)b.x; h[5]=(f16)b.y; h[6]=(f16)b.z; h[7]=(f16)b.w;
        *reinterpret_cast<f16x8*>(xlb + xl_off(row, seg * 8)) = h;
    }

#pragma unroll 1
    for (int l = 0; l < NLAY; ++l) {
        const f16* Vl = Vh  + (size_t)l * 256 * DDIM;
        const f16* Ul = Uh  + (size_t)l * NEXP * DDIM * RLOW;
        const f16* Cl = Ch  + (size_t)l * NEXP * RLOW * RLOW;
        const f16* Wl = Wgh + (size_t)l * 16 * DDIM;
        const float* bl = bias + (size_t)l * DDIM;
        const int last = (l == NLAY - 1);

        const f16* B0 = Vl + (size_t)(2 * wv * 16 + l16) * DDIM + lhi * 8;
        const f16* B1 = Vl + (size_t)((2 * wv + 1) * 16 + l16) * DDIM + lhi * 8;
        const f16* BG = Wl + (size_t)l16 * DDIM + lhi * 8;

        // ---- G1-HEAD PREFETCH (pre-barrier): kt=0..1 only (24 regs)
        f16x8 pb0[2], pb1[2], pbg[2];
#pragma unroll
        for (int kp = 0; kp < 2; ++kp) {
            pb0[kp] = *reinterpret_cast<const f16x8*>(B0 + kp * 32);
            pb1[kp] = *reinterpret_cast<const f16x8*>(B1 + kp * 32);
            pbg[kp] = *reinterpret_cast<const f16x8*>(BG + kp * 32);
        }

        __syncthreads();   // top: s_xl ready; prev-layer s_v reads done

        // ===== GEMM-1: v = tanh(xl @ V^T); wave owns n-tiles {2wv, 2wv+1};
        //       gate logits redundantly per wave. Swapped operands.
        f32x4 a0[4], a1[4], ag[4];
#pragma unroll
        for (int mt = 0; mt < 4; ++mt) {
            a0[mt] = (f32x4){0.f,0.f,0.f,0.f};
            a1[mt] = (f32x4){0.f,0.f,0.f,0.f};
            ag[mt] = (f32x4){0.f,0.f,0.f,0.f};
        }
        // prologue: prefetched kt 0..1
#pragma unroll
        for (int kt = 0; kt < 2; ++kt) {
#pragma unroll
            for (int mt = 0; mt < 4; ++mt) {
                f16x8 af = *reinterpret_cast<const f16x8*>(
                    xlb + xl_off(mt * 16 + l16, kt * 32 + lhi * 8));
                a0[mt] = mfma16(pb0[kt], af, a0[mt]);
                a1[mt] = mfma16(pb1[kt], af, a1[mt]);
                ag[mt] = mfma16(pbg[kt], af, ag[mt]);
            }
        }
        // main: kt 2..31
#pragma unroll 4
        for (int kt = 2; kt < 32; ++kt) {
            f16x8 b0 = *reinterpret_cast<const f16x8*>(B0 + kt * 32);
            f16x8 b1 = *reinterpret_cast<const f16x8*>(B1 + kt * 32);
            f16x8 bg = *reinterpret_cast<const f16x8*>(BG + kt * 32);
#pragma unroll
            for (int mt = 0; mt < 4; ++mt) {
                f16x8 af = *reinterpret_cast<const f16x8*>(
                    xlb + xl_off(mt * 16 + l16, kt * 32 + lhi * 8));
                a0[mt] = mfma16(b0, af, a0[mt]);
                a1[mt] = mfma16(b1, af, a1[mt]);
                ag[mt] = mfma16(bg, af, ag[mt]);
            }
        }

        // gate softmax: ag[mt] = logits[e=4lhi+r][m=mt*16+l16]; lhi==0 lanes
        // hold all 4 experts locally -> lane-local softmax + shfl broadcast.
        float gmy[4];
#pragma unroll
        for (int mt = 0; mt < 4; ++mt) {
            float e0 = ag[mt][0], e1 = ag[mt][1], e2 = ag[mt][2], e3 = ag[mt][3];
            float mx = fmaxf(fmaxf(e0, e1), fmaxf(e2, e3));
            float x0e = __expf(e0 - mx), x1e = __expf(e1 - mx);
            float x2e = __expf(e2 - mx), x3e = __expf(e3 - mx);
            float inv = 1.0f / (x0e + x1e + x2e + x3e);
            float ge = (eown == 0) ? x0e : (eown == 1) ? x1e : (eown == 2) ? x2e : x3e;
            gmy[mt] = __shfl(ge * inv, l16);
        }

        // write v: per (tile, mt) 4 consecutive n -> one ds_write_b64
#pragma unroll
        for (int mt = 0; mt < 4; ++mt) {
            const int m = mt * 16 + l16;
            f16x4v w0, w1;
#pragma unroll
            for (int r = 0; r < 4; ++r) {
                w0[r] = (f16)ftanh(a0[mt][r]);
                w1[r] = (f16)ftanh(a1[mt][r]);
            }
            *reinterpret_cast<f16x4v*>(svb + sv_off(m, (2 * wv) * 16 + lhi * 4))     = w0;
            *reinterpret_cast<f16x4v*>(svb + sv_off(m, (2 * wv + 1) * 16 + lhi * 4)) = w1;
        }

        __syncthreads();   // barrier-1: v complete

        // ===== GEMM-2 operand fetch + G2-HEAD C prefetch (pre-barrier-2a)
        f16x8 caf[4][2];   // [mt][kt2]
#pragma unroll
        for (int mt = 0; mt < 4; ++mt)
#pragma unroll
            for (int kt2 = 0; kt2 < 2; ++kt2)
                caf[mt][kt2] = *reinterpret_cast<const f16x8*>(
                    svb + sv_off(mt * 16 + l16, eown * 64 + kt2 * 32 + lhi * 8));
        f16x8 cb0[2], cb1[2];   // C weight prefetch (global, race-free)
        {
            const f16* CB0 = Cl + (size_t)(eown * 64 + hown * 32 + l16) * RLOW + lhi * 8;
            const f16* CB1 = CB0 + 16 * RLOW;
#pragma unroll
            for (int kt2 = 0; kt2 < 2; ++kt2) {
                cb0[kt2] = *reinterpret_cast<const f16x8*>(CB0 + kt2 * 32);
                cb1[kt2] = *reinterpret_cast<const f16x8*>(CB1 + kt2 * 32);
            }
        }

        __syncthreads();   // barrier-2a: all v reads done

        {
            f32x4 c2[4][2];
#pragma unroll
            for (int mt = 0; mt < 4; ++mt) {
                c2[mt][0] = (f32x4){0.f,0.f,0.f,0.f};
                c2[mt][1] = (f32x4){0.f,0.f,0.f,0.f};
            }
#pragma unroll
            for (int kt2 = 0; kt2 < 2; ++kt2) {
#pragma unroll
                for (int mt = 0; mt < 4; ++mt) {
                    c2[mt][0] = mfma16(cb0[kt2], caf[mt][kt2], c2[mt][0]);
                    c2[mt][1] = mfma16(cb1[kt2], caf[mt][kt2], c2[mt][1]);
                }
            }
            // p = g * tanh(c); per (mt, ntc) 4 consecutive cols -> ds_write_b64
#pragma unroll
            for (int mt = 0; mt < 4; ++mt) {
                const int m = mt * 16 + l16;
#pragma unroll
                for (int ntc = 0; ntc < 2; ++ntc) {
                    f16x4v w;
#pragma unroll
                    for (int r = 0; r < 4; ++r)
                        w[r] = (f16)(ftanh(c2[mt][ntc][r]) * gmy[mt]);
                    const int col = eown * 64 + hown * 32 + ntc * 16 + lhi * 4;
                    *reinterpret_cast<f16x4v*>(svb + sv_off(m, col)) = w;
                }
            }
        }

        // ---- G3-HEAD U prefetch (pre-barrier-2; independent of p)
        f16x8 uf0[4];
#pragma unroll
        for (int dt = 0; dt < 4; ++dt)
            uf0[dt] = *reinterpret_cast<const f16x8*>(
                Ul + (size_t)(wv * 128 + dt * 16 + l16) * RLOW + lhi * 8);

        __syncthreads();   // barrier-2: p complete

        // ===== GEMM-3: out = p @ U^T; wave owns d in [wv*128, +128), 2 passes.
#pragma unroll
        for (int ps = 0; ps < 2; ++ps) {
            const int dbase = wv * 128 + ps * 64;
            f32x4 c3[4][4];   // [dt][mt]
#pragma unroll
            for (int dt = 0; dt < 4; ++dt)
#pragma unroll
                for (int mt = 0; mt < 4; ++mt) c3[dt][mt] = (f32x4){0.f,0.f,0.f,0.f};
#pragma unroll 4
            for (int kt = 0; kt < 8; ++kt) {
                f16x8 af[4];
#pragma unroll
                for (int mt = 0; mt < 4; ++mt)
                    af[mt] = *reinterpret_cast<const f16x8*>(
                        svb + sv_off(mt * 16 + l16, kt * 32 + lhi * 8));
#pragma unroll
                for (int dt = 0; dt < 4; ++dt) {
                    f16x8 bf;
                    if (ps == 0 && kt == 0) bf = uf0[dt];
                    else bf = *reinterpret_cast<const f16x8*>(
                        Ul + (size_t)(kt >> 1) * DDIM * RLOW
                           + (size_t)(dbase + dt * 16 + l16) * RLOW + (kt & 1) * 32 + lhi * 8);
#pragma unroll
                    for (int mt = 0; mt < 4; ++mt)
                        c3[dt][mt] = mfma16(bf, af[mt], c3[dt][mt]);
                }
            }
            // epilogue (vectorized, x0 loads inline as in R13)
            f32x4 biasv[4];
#pragma unroll
            for (int dt = 0; dt < 4; ++dt)
                biasv[dt] = *reinterpret_cast<const f32x4*>(bl + dbase + dt * 16 + lhi * 4);
#pragma unroll
            for (int dt = 0; dt < 4; ++dt) {
                const int d0 = dbase + dt * 16 + lhi * 4;
#pragma unroll
                for (int mt = 0; mt < 4; ++mt) {
                    const int m = mt * 16 + l16;
                    f32x4 x0v = *reinterpret_cast<const f32x4*>(
                        x + (size_t)(row0 + m) * DDIM + d0);
                    f32x4 xlv;
                    if (l == 0) {
                        xlv = x0v;                          // layer 0: xl == x0 (f32)
                    } else {
                        f16x4v h = *reinterpret_cast<const f16x4v*>(xlb + xl_off(m, d0));
                        xlv[0] = (float)h[0]; xlv[1] = (float)h[1];
                        xlv[2] = (float)h[2]; xlv[3] = (float)h[3];
                    }
                    f32x4 y;
#pragma unroll
                    for (int r = 0; r < 4; ++r)
                        y[r] = fmaf(c3[dt][mt][r] + biasv[dt][r], x0v[r], xlv[r]);
                    if (!last) {
                        f16x4v hw;
#pragma unroll
                        for (int r = 0; r < 4; ++r) hw[r] = (f16)ftanh(y[r]);
                        *reinterpret_cast<f16x4v*>(xlb + xl_off(m, d0)) = hw;
                    } else {
                        __builtin_nontemporal_store(y,
                            reinterpret_cast<f32x4*>(out + (size_t)(row0 + m) * DDIM + d0));
                    }
                }
            }
        }
    }
}

extern "C" void kernel_launch(void* const* d_in, const int* in_sizes, int n_in,
                              void* d_out, int out_size, void* d_ws, size_t ws_size,
                              hipStream_t stream)
{
    const float* x  = (const float*)d_in[0];
    const float* U  = (const float*)d_in[1];
    const float* V  = (const float*)d_in[2];
    const float* C  = (const float*)d_in[3];
    const float* Wg = (const float*)d_in[4];
    const float* bb = (const float*)d_in[5];
    float* out = (float*)d_out;

    const size_t sUV = (size_t)NEXP * DDIM * RLOW;          // 262144 per layer
    const size_t sC  = (size_t)NEXP * RLOW * RLOW;          // 16384  per layer
    const size_t sW  = (size_t)16 * DDIM;                   // 16384  per layer

    f16* Vh  = (f16*)d_ws;                                  // 1.5 MB
    f16* Uh  = Vh + NLAY * sUV;                             // 1.5 MB
    f16* Chh = Uh + NLAY * sUV;                             // 96 KB
    f16* Wgh = Chh + NLAY * sC;                             // 96 KB

    int n4v = (int)(NLAY * sUV / 4);
    cast_f32_to_f16<<<(n4v + 255) / 256, 256, 0, stream>>>(V, Vh, n4v);
    cast_f32_to_f16<<<(n4v + 255) / 256, 256, 0, stream>>>(U, Uh, n4v);
    int n4c = (int)(NLAY * sC / 4);
    cast_f32_to_f16<<<(n4c + 255) / 256, 256, 0, stream>>>(C, Chh, n4c);
    build_wgh<<<(int)(NLAY * sW / 256), 256, 0, stream>>>(Wg, Wgh);

    crossnet_fused<<<dim3(B_TOT / BT), dim3(512), 0, stream>>>(
        x, out, Uh, Vh, Chh, Wgh, bb);
}

// Round 20
// 194.913 us; speedup vs baseline: 1.0634x; 1.0634x over previous
//
#include <hip/hip_runtime.h>
#include <hip/hip_bf16.h>

// CrossNetMoE fully fused, BT=64 rows/WG, 512 threads, grid=256 (1 WG/CU).
// L=3, E=4, D=1024, R=64, B=16384. LDS 160KB: s_xl 128KB + s_v 32KB.
// FINAL (== R13, the measured optimum of 19 variants: 196us, VGPR 88, no
// spill). Key techniques, each verified by counter deltas:
//  - all 3 layers fused, xl resident in swizzled f16 LDS (traffic 650->130MB)
//  - f16 MFMA 16x16x32 with OPERAND-SWAP: mfma16(weight, xl) transposes the
//    D-tile so each lane holds 4 consecutive n/d outputs for one row m ->
//    ds_write_b64 v/p, f32x4 epilogue load/store, lane-local gate softmax
//    (261->196us). Frag map: k=8*(lane>>4)+j; D row=4*(lane>>4)+reg (weight
//    axis), col=lane&15 (m axis) [learn_hip m89].
//  - gate folded into G1 as a zero-padded 16-row Wg tile, per-wave redundant
//  - XOR-swizzled LDS (byte ^= (row&7)<<4) for bank-balance
// Toolchain lore (R5-R19): 512-thr blocks have a HARD 128 arch-VGPR cap
// (1024-thr: 64). Every cross-barrier prefetch/hoist attempt (R14,R15,R18,
// R19) tipped into scratch spill (WRITE 67->105+MB) and lost; co-residency
// at 80KB LDS (R17) and wave-local barrier removal (R16) also lost. This
// structure at 2 waves/SIMD is the local optimum.

typedef _Float16 f16;
typedef f16  f16x4v __attribute__((ext_vector_type(4)));
typedef f16  f16x8 __attribute__((ext_vector_type(8)));
typedef float f32x4 __attribute__((ext_vector_type(4)));

#define B_TOT 16384
#define DDIM  1024
#define RLOW  64
#define NEXP  4
#define NLAY  3
#define BT    64

__device__ __forceinline__ float ftanh(float x) {
    float e2 = __expf(2.0f * x);          // inf-safe: ->1 / ->-1
    return 1.0f - 2.0f / (e2 + 1.0f);
}
__device__ __forceinline__ f32x4 mfma16(f16x8 a, f16x8 b, f32x4 c) {
    return __builtin_amdgcn_mfma_f32_16x16x32_f16(a, b, c, 0, 0, 0);
}
// swizzled byte offsets: row-stride 2048B (s_xl) / 512B (s_v); XOR bits 4-6
__device__ __forceinline__ int xl_off(int row, int col) {
    return row * 2048 + ((col * 2) ^ ((row & 7) << 4));
}
__device__ __forceinline__ int sv_off(int row, int col) {
    return row * 512 + ((col * 2) ^ ((row & 7) << 4));
}

__global__ void cast_f32_to_f16(const float* __restrict__ in,
                                f16* __restrict__ out, int n4) {
    int i = blockIdx.x * 256 + threadIdx.x;
    if (i < n4) {
        float4 v = reinterpret_cast<const float4*>(in)[i];
        f16 h0 = (f16)v.x, h1 = (f16)v.y, h2 = (f16)v.z, h3 = (f16)v.w;
        short4 pk;
        pk.x = __builtin_bit_cast(short, h0); pk.y = __builtin_bit_cast(short, h1);
        pk.z = __builtin_bit_cast(short, h2); pk.w = __builtin_bit_cast(short, h3);
        reinterpret_cast<short4*>(out)[i] = pk;
    }
}

// Wgh[l][16][1024] f16: rows 0-3 = Wg experts, rows 4-15 = 0.
__global__ void build_wgh(const float* __restrict__ Wg, f16* __restrict__ Wgh) {
    int i = blockIdx.x * 256 + threadIdx.x;          // < 3*16*1024
    int l = i >> 14, r = (i >> 10) & 15, k = i & 1023;
    f16 v = (f16)0.f;
    if (r < NEXP) v = (f16)Wg[(size_t)(l * NEXP + r) * DDIM + k];
    Wgh[i] = v;
}

__global__ __launch_bounds__(512, 1) void crossnet_fused(
    const float* __restrict__ x, float* __restrict__ out,
    const f16* __restrict__ Uh,   // [L][E][D][R]
    const f16* __restrict__ Vh,   // [L][256][1024]
    const f16* __restrict__ Ch,   // [L][E][64][64]
    const f16* __restrict__ Wgh,  // [L][16][1024]
    const float* __restrict__ bias)  // [L][1024]
{
    __shared__ f16 s_xl[BT * 1024];   // 128 KB, swizzled
    __shared__ f16 s_v[BT * 256];     //  32 KB, swizzled (v then p)

    const int tid  = threadIdx.x;
    const int lane = tid & 63;
    const int wv   = tid >> 6;        // 0..7
    const int l16  = lane & 15;
    const int lhi  = lane >> 4;       // 0..3
    const int row0 = blockIdx.x * BT;
    const int eown = wv >> 1;         // this wave's expert for GEMM-2
    const int hown = wv & 1;

    char* const xlb = (char*)s_xl;
    char* const svb = (char*)s_v;

    // ---- stage x -> s_xl (f16, swizzled): 64 rows x 1024 cols
#pragma unroll
    for (int j = 0; j < 16; ++j) {
        int f = tid + j * 512;        // 0..8191
        int row = f >> 7, seg = f & 127;
        const float4* sp = reinterpret_cast<const float4*>(
            x + (size_t)(row0 + row) * DDIM + seg * 8);
        float4 a = sp[0], b = sp[1];
        f16x8 h;
        h[0]=(f16)a.x; h[1]=(f16)a.y; h[2]=(f16)a.z; h[3]=(f16)a.w;
        h[4]=(f16)b.x; h[5]=(f16)b.y; h[6]=(f16)b.z; h[7]=(f16)b.w;
        *reinterpret_cast<f16x8*>(xlb + xl_off(row, seg * 8)) = h;
    }

#pragma unroll 1
    for (int l = 0; l < NLAY; ++l) {
        const f16* Vl = Vh  + (size_t)l * 256 * DDIM;
        const f16* Ul = Uh  + (size_t)l * NEXP * DDIM * RLOW;
        const f16* Cl = Ch  + (size_t)l * NEXP * RLOW * RLOW;
        const f16* Wl = Wgh + (size_t)l * 16 * DDIM;
        const float* bl = bias + (size_t)l * DDIM;
        const int last = (l == NLAY - 1);

        __syncthreads();   // top: s_xl ready; prev-layer s_v reads done

        // ===== GEMM-1: v = tanh(xl @ V^T); wave owns n-tiles {2wv, 2wv+1};
        //       gate logits redundantly per wave. Swapped operands:
        //       D row(4lhi+r)=n-in-tile, col(l16)=m.
        const f16* B0 = Vl + (size_t)(2 * wv * 16 + l16) * DDIM + lhi * 8;
        const f16* B1 = Vl + (size_t)((2 * wv + 1) * 16 + l16) * DDIM + lhi * 8;
        const f16* BG = Wl + (size_t)l16 * DDIM + lhi * 8;
        f32x4 a0[4], a1[4], ag[4];
#pragma unroll
        for (int mt = 0; mt < 4; ++mt) {
            a0[mt] = (f32x4){0.f,0.f,0.f,0.f};
            a1[mt] = (f32x4){0.f,0.f,0.f,0.f};
            ag[mt] = (f32x4){0.f,0.f,0.f,0.f};
        }
#pragma unroll 4
        for (int kt = 0; kt < 32; ++kt) {
            f16x8 b0 = *reinterpret_cast<const f16x8*>(B0 + kt * 32);
            f16x8 b1 = *reinterpret_cast<const f16x8*>(B1 + kt * 32);
            f16x8 bg = *reinterpret_cast<const f16x8*>(BG + kt * 32);
#pragma unroll
            for (int mt = 0; mt < 4; ++mt) {
                f16x8 af = *reinterpret_cast<const f16x8*>(
                    xlb + xl_off(mt * 16 + l16, kt * 32 + lhi * 8));
                a0[mt] = mfma16(b0, af, a0[mt]);
                a1[mt] = mfma16(b1, af, a1[mt]);
                ag[mt] = mfma16(bg, af, ag[mt]);
            }
        }

        // gate softmax: ag[mt] holds logits[e=4*lhi+r][m=mt*16+l16]; lanes
        // lhi==0 own e=0..3 locally -> lane-local softmax, shfl broadcast.
        float gmy[4];
#pragma unroll
        for (int mt = 0; mt < 4; ++mt) {
            float e0 = ag[mt][0], e1 = ag[mt][1], e2 = ag[mt][2], e3 = ag[mt][3];
            float mx = fmaxf(fmaxf(e0, e1), fmaxf(e2, e3));
            float x0e = __expf(e0 - mx), x1e = __expf(e1 - mx);
            float x2e = __expf(e2 - mx), x3e = __expf(e3 - mx);
            float inv = 1.0f / (x0e + x1e + x2e + x3e);
            float ge = (eown == 0) ? x0e : (eown == 1) ? x1e : (eown == 2) ? x2e : x3e;
            gmy[mt] = __shfl(ge * inv, l16);   // from the lhi==0 lane owning m
        }

        // write v: per (tile, mt) 4 consecutive n -> one ds_write_b64
#pragma unroll
        for (int mt = 0; mt < 4; ++mt) {
            const int m = mt * 16 + l16;
            f16x4v w0, w1;
#pragma unroll
            for (int r = 0; r < 4; ++r) {
                w0[r] = (f16)ftanh(a0[mt][r]);
                w1[r] = (f16)ftanh(a1[mt][r]);
            }
            *reinterpret_cast<f16x4v*>(svb + sv_off(m, (2 * wv) * 16 + lhi * 4))     = w0;
            *reinterpret_cast<f16x4v*>(svb + sv_off(m, (2 * wv + 1) * 16 + lhi * 4)) = w1;
        }

        __syncthreads();   // barrier-1: v complete

        // ===== GEMM-2: p = g * tanh(C_e @ v); wave -> expert eown, half hown
        f16x8 caf[4][2];   // [mt][kt2]  (A-role frags, slot-2)
#pragma unroll
        for (int mt = 0; mt < 4; ++mt)
#pragma unroll
            for (int kt2 = 0; kt2 < 2; ++kt2)
                caf[mt][kt2] = *reinterpret_cast<const f16x8*>(
                    svb + sv_off(mt * 16 + l16, eown * 64 + kt2 * 32 + lhi * 8));

        __syncthreads();   // barrier-2a: all v reads done

        {
            f32x4 c2[4][2];
#pragma unroll
            for (int mt = 0; mt < 4; ++mt) {
                c2[mt][0] = (f32x4){0.f,0.f,0.f,0.f};
                c2[mt][1] = (f32x4){0.f,0.f,0.f,0.f};
            }
            const f16* CB0 = Cl + (size_t)(eown * 64 + hown * 32 + l16) * RLOW + lhi * 8;
            const f16* CB1 = CB0 + 16 * RLOW;
#pragma unroll
            for (int kt2 = 0; kt2 < 2; ++kt2) {
                f16x8 cb0 = *reinterpret_cast<const f16x8*>(CB0 + kt2 * 32);
                f16x8 cb1 = *reinterpret_cast<const f16x8*>(CB1 + kt2 * 32);
#pragma unroll
                for (int mt = 0; mt < 4; ++mt) {
                    c2[mt][0] = mfma16(cb0, caf[mt][kt2], c2[mt][0]);
                    c2[mt][1] = mfma16(cb1, caf[mt][kt2], c2[mt][1]);
                }
            }
            // p = g * tanh(c); per (mt, ntc) 4 consecutive cols -> ds_write_b64
#pragma unroll
            for (int mt = 0; mt < 4; ++mt) {
                const int m = mt * 16 + l16;
#pragma unroll
                for (int ntc = 0; ntc < 2; ++ntc) {
                    f16x4v w;
#pragma unroll
                    for (int r = 0; r < 4; ++r)
                        w[r] = (f16)(ftanh(c2[mt][ntc][r]) * gmy[mt]);
                    const int col = eown * 64 + hown * 32 + ntc * 16 + lhi * 4;
                    *reinterpret_cast<f16x4v*>(svb + sv_off(m, col)) = w;
                }
            }
        }

        __syncthreads();   // barrier-2: p complete

        // ===== GEMM-3: out = p @ U^T; wave owns d in [wv*128, +128), 2 passes.
        //       Swapped: acc[dt][mt] row(4lhi+r)=d-in-tile, col(l16)=m.
#pragma unroll 1
        for (int ps = 0; ps < 2; ++ps) {
            const int dbase = wv * 128 + ps * 64;
            f32x4 c3[4][4];   // [dt][mt]
#pragma unroll
            for (int dt = 0; dt < 4; ++dt)
#pragma unroll
                for (int mt = 0; mt < 4; ++mt) c3[dt][mt] = (f32x4){0.f,0.f,0.f,0.f};
#pragma unroll 4
            for (int kt = 0; kt < 8; ++kt) {
                f16x8 af[4];
#pragma unroll
                for (int mt = 0; mt < 4; ++mt)
                    af[mt] = *reinterpret_cast<const f16x8*>(
                        svb + sv_off(mt * 16 + l16, kt * 32 + lhi * 8));
#pragma unroll
                for (int dt = 0; dt < 4; ++dt) {
                    const f16* ub = Ul + (size_t)(kt >> 1) * DDIM * RLOW
                        + (size_t)(dbase + dt * 16 + l16) * RLOW + (kt & 1) * 32 + lhi * 8;
                    f16x8 bf = *reinterpret_cast<const f16x8*>(ub);
#pragma unroll
                    for (int mt = 0; mt < 4; ++mt)
                        c3[dt][mt] = mfma16(bf, af[mt], c3[dt][mt]);
                }
            }
            // epilogue (vectorized): per (dt,mt): d0..d0+3 for one row m
            f32x4 biasv[4];
#pragma unroll
            for (int dt = 0; dt < 4; ++dt)
                biasv[dt] = *reinterpret_cast<const f32x4*>(bl + dbase + dt * 16 + lhi * 4);
#pragma unroll
            for (int dt = 0; dt < 4; ++dt) {
                const int d0 = dbase + dt * 16 + lhi * 4;
#pragma unroll
                for (int mt = 0; mt < 4; ++mt) {
                    const int m = mt * 16 + l16;
                    f32x4 x0v = *reinterpret_cast<const f32x4*>(
                        x + (size_t)(row0 + m) * DDIM + d0);
                    f32x4 xlv;
                    if (l == 0) {
                        xlv = x0v;                          // layer 0: xl == x0 (f32)
                    } else {
                        f16x4v h = *reinterpret_cast<const f16x4v*>(xlb + xl_off(m, d0));
                        xlv[0] = (float)h[0]; xlv[1] = (float)h[1];
                        xlv[2] = (float)h[2]; xlv[3] = (float)h[3];
                    }
                    f32x4 y;
#pragma unroll
                    for (int r = 0; r < 4; ++r)
                        y[r] = fmaf(c3[dt][mt][r] + biasv[dt][r], x0v[r], xlv[r]);
                    if (!last) {
                        f16x4v hw;
#pragma unroll
                        for (int r = 0; r < 4; ++r) hw[r] = (f16)ftanh(y[r]);
                        *reinterpret_cast<f16x4v*>(xlb + xl_off(m, d0)) = hw;
                    } else {
                        __builtin_nontemporal_store(y,
                            reinterpret_cast<f32x4*>(out + (size_t)(row0 + m) * DDIM + d0));
                    }
                }
            }
        }
    }
}

extern "C" void kernel_launch(void* const* d_in, const int* in_sizes, int n_in,
                              void* d_out, int out_size, void* d_ws, size_t ws_size,
                              hipStream_t stream)
{
    const float* x  = (const float*)d_in[0];
    const float* U  = (const float*)d_in[1];
    const float* V  = (const float*)d_in[2];
    const float* C  = (const float*)d_in[3];
    const float* Wg = (const float*)d_in[4];
    const float* bb = (const float*)d_in[5];
    float* out = (float*)d_out;

    const size_t sUV = (size_t)NEXP * DDIM * RLOW;          // 262144 per layer
    const size_t sC  = (size_t)NEXP * RLOW * RLOW;          // 16384  per layer
    const size_t sW  = (size_t)16 * DDIM;                   // 16384  per layer

    f16* Vh  = (f16*)d_ws;                                  // 1.5 MB
    f16* Uh  = Vh + NLAY * sUV;                             // 1.5 MB
    f16* Chh = Uh + NLAY * sUV;                             // 96 KB
    f16* Wgh = Chh + NLAY * sC;                             // 96 KB

    int n4v = (int)(NLAY * sUV / 4);
    cast_f32_to_f16<<<(n4v + 255) / 256, 256, 0, stream>>>(V, Vh, n4v);
    cast_f32_to_f16<<<(n4v + 255) / 256, 256, 0, stream>>>(U, Uh, n4v);
    int n4c = (int)(NLAY * sC / 4);
    cast_f32_to_f16<<<(n4c + 255) / 256, 256, 0, stream>>>(C, Chh, n4c);
    build_wgh<<<(int)(NLAY * sW / 256), 256, 0, stream>>>(Wg, Wgh);

    crossnet_fused<<<dim3(B_TOT / BT), dim3(512), 0, stream>>>(
        x, out, Uh, Vh, Chh, Wgh, bb);
}